// Round 4
// baseline (135.817 us; speedup 1.0000x reference)
//
#include <hip/hip_runtime.h>
#include <math.h>

// Problem constants (B,C,H,W = 8,256,64,64; N = H*W = 4096)
#define BQ 8
#define CQ 256
#define NQ 4096
#define MT 128          // m-tile per block
#define NSTEP (NQ / 32) // 128 K-chunks of 32

typedef short s16x8 __attribute__((ext_vector_type(8)));
typedef short s16x4 __attribute__((ext_vector_type(4)));
typedef float f32x4 __attribute__((ext_vector_type(4)));

static __device__ __forceinline__ float4 ld4(const float* p) { return *(const float4*)p; }

static constexpr float LOG2E = 1.4426950408889634f;

static __device__ __forceinline__ short f2bf(float f) {
    return __builtin_bit_cast(short, (__bf16)f);
}

// -------- K1: f' = (wq.x)*log2e, g = wk.x, xbf = bf16(x) --------
// grid (NQ/64, BQ) x 256thr: 4-way c-split per block for wave count (8 waves/CU).
__global__ void k_fg(const float* __restrict__ x, const float* __restrict__ wq,
                     const float* __restrict__ wk, float* __restrict__ fs,
                     float* __restrict__ g, short* __restrict__ xbf) {
    int b = blockIdx.y;
    int nloc = threadIdx.x & 63;
    int cg = threadIdx.x >> 6;           // 0..3 c-group
    int n = blockIdx.x * 64 + nloc;
    const float* xb = x + (size_t)b * CQ * NQ + n;
    short* xo = xbf + (size_t)b * CQ * NQ + n;
    float accf = 0.f, accg = 0.f;
    int c0 = cg * 64;
#pragma unroll 8
    for (int c = c0; c < c0 + 64; ++c) {
        float v = xb[(size_t)c * NQ];
        accf = fmaf(wq[c], v, accf);
        accg = fmaf(wk[c], v, accg);
        xo[(size_t)c * NQ] = f2bf(v);
    }
    __shared__ float sf[4][64], sg2[4][64];
    sf[cg][nloc] = accf;
    sg2[cg][nloc] = accg;
    __syncthreads();
    if (threadIdx.x < 64) {
        float f = sf[0][nloc] + sf[1][nloc] + sf[2][nloc] + sf[3][nloc];
        float gg = sg2[0][nloc] + sg2[1][nloc] + sg2[2][nloc] + sg2[3][nloc];
        fs[b * NQ + blockIdx.x * 64 + nloc] = f * LOG2E;
        g[b * NQ + blockIdx.x * 64 + nloc] = gg;
    }
}

// -------- K1b: per-batch max/min of f' --------
__global__ void k_minmax(const float* __restrict__ fs, float* __restrict__ fmx,
                         float* __restrict__ fmn) {
    int b = blockIdx.x;
    const float* f = fs + b * NQ;
    float mx = -1e30f, mn = 1e30f;
    for (int i = threadIdx.x; i < NQ; i += 256) {
        float v = f[i];
        mx = fmaxf(mx, v);
        mn = fminf(mn, v);
    }
    for (int off = 32; off; off >>= 1) {
        mx = fmaxf(mx, __shfl_down(mx, off));
        mn = fminf(mn, __shfl_down(mn, off));
    }
    __shared__ float smx[4], smn[4];
    int wid = threadIdx.x >> 6;
    if ((threadIdx.x & 63) == 0) { smx[wid] = mx; smn[wid] = mn; }
    __syncthreads();
    if (threadIdx.x == 0) {
        mx = fmaxf(fmaxf(smx[0], smx[1]), fmaxf(smx[2], smx[3]));
        mn = fminf(fminf(smn[0], smn[1]), fminf(smn[2], smn[3]));
        fmx[b] = mx;
        fmn[b] = mn;
    }
}

// -------- K2 fused: y[c][m] = sum_n x[c][n] e[n,m];  o = (1-g)*wv*(y/Z) + g*x --------
// 256 thr (4 waves: wc = w&1 c-half, wm = w>>1 m-half). Block tile 256c x 128m.
// Wave tile 128c x 64m (jc=8 x jm=4): 8 LDS A-reads feed 32 MFMA/step (4x B-reuse).
// LDS 64KB -> 2 blocks/CU (co-resident block hides barrier drain).
// Epilogue: y/Z -> bf16 -> m-major swizzled LDS, GEMM2 (wv * y_norm, K=256) fused.
__global__ void __launch_bounds__(256, 2) k_attn(
    const short* __restrict__ xbf, const float* __restrict__ fsp,
    const float* __restrict__ gp, const float* __restrict__ fmxs,
    const float* __restrict__ fmns, const float* __restrict__ wv,
    const float* __restrict__ x, const float* __restrict__ gamma,
    float* __restrict__ out) {
    __shared__ __align__(16) char smem[65536];  // stage dbuf [0,32KB); y_lds overlays [0,64KB)

    int bid = blockIdx.x;
    int b = bid & 7;            // batch -> XCD affinity (2MB xbf slice per XCD L2)
    int mblk = bid >> 3;        // 0..31
    int m0 = mblk * MT;
    int tid = threadIdx.x;
    int l = tid & 63;
    int w = tid >> 6;           // 0..3
    int wc = w & 1;             // c-half
    int wm = w >> 1;            // m-half
    int q = l >> 4;             // k-slot
    int cr = l & 15;            // A-row / B-col within frag

    float fmx = fmxs[b], fmn = fmns[b];
    const float* gb = gp + b * NQ;
    float gj[4], nM[4], zac[4];
#pragma unroll
    for (int jm = 0; jm < 4; ++jm) {
        float gv = gb[m0 + wm * 64 + jm * 16 + cr];
        gj[jm] = gv;
        nM[jm] = -((gv >= 0.f) ? gv * fmx : gv * fmn);
        zac[jm] = 0.f;
    }

    const float* fb = fsp + b * NQ;
    const short* xb = xbf + (size_t)b * CQ * NQ;

    f32x4 acc[8][4];
#pragma unroll
    for (int jc = 0; jc < 8; ++jc)
#pragma unroll
        for (int jm = 0; jm < 4; ++jm) acc[jc][jm] = (f32x4){0.f, 0.f, 0.f, 0.f};

    // ---- stage chunk 0 (tile 256c x 32n bf16 = 16KB; linear [c][64B]) ----
#pragma unroll
    for (int r2 = 0; r2 < 4; ++r2) {
        int off = tid * 16 + r2 * 4096;
        int row = off >> 6, nb = off & 63;
        const short* src = xb + (size_t)row * NQ + (nb >> 1);
        __builtin_amdgcn_global_load_lds(
            (const __attribute__((address_space(1))) void*)src,
            (__attribute__((address_space(3))) void*)(smem + off), 16, 0, 0);
    }
    float4 fqa = *(const float4*)(fb + q * 8);
    float4 fqb = *(const float4*)(fb + q * 8 + 4);
    __syncthreads();

    for (int t = 0; t < NSTEP; ++t) {
        const char* cbuf = smem + (t & 1) * 16384;
        int n0n = ((t + 1) & (NSTEP - 1)) * 32;
        if (t + 1 < NSTEP) {
            char* nbuf = smem + ((t + 1) & 1) * 16384;
#pragma unroll
            for (int r2 = 0; r2 < 4; ++r2) {
                int off = tid * 16 + r2 * 4096;
                int row = off >> 6, nb = off & 63;
                const short* src = xb + (size_t)row * NQ + n0n + (nb >> 1);
                __builtin_amdgcn_global_load_lds(
                    (const __attribute__((address_space(1))) void*)src,
                    (__attribute__((address_space(3))) void*)(nbuf + off), 16, 0, 0);
            }
        }
        float4 fqa_n = *(const float4*)(fb + n0n + q * 8);
        float4 fqb_n = *(const float4*)(fb + n0n + q * 8 + 4);
        // e-gen: 4 jm B-frags in registers + running Z
        float fq[8] = {fqa.x, fqa.y, fqa.z, fqa.w, fqb.x, fqb.y, fqb.z, fqb.w};
        s16x8 bv[4];
#pragma unroll
        for (int jm = 0; jm < 4; ++jm) {
            float z = zac[jm];
#pragma unroll
            for (int i = 0; i < 8; ++i) {
                float e = __builtin_amdgcn_exp2f(fmaf(fq[i], gj[jm], nM[jm]));
                z += e;
                bv[jm][i] = f2bf(e);
            }
            zac[jm] = z;
        }
        // A-frags from LDS, 4x reuse across jm
#pragma unroll
        for (int jc = 0; jc < 8; ++jc) {
            s16x8 av = *(const s16x8*)(cbuf + (wc * 128 + jc * 16 + cr) * 64 + q * 16);
#pragma unroll
            for (int jm = 0; jm < 4; ++jm)
                acc[jc][jm] = __builtin_amdgcn_mfma_f32_16x16x32_bf16(av, bv[jm], acc[jc][jm], 0, 0, 0);
        }
        fqa = fqa_n;
        fqb = fqb_n;
        __syncthreads();   // drains stage vmcnt + releases cur buffer
    }

    // ---- Z finalize: butterfly over the 4 k-slot groups ----
    float rzl[4];
#pragma unroll
    for (int jm = 0; jm < 4; ++jm) {
        float z = zac[jm];
        z += __shfl_xor(z, 16);
        z += __shfl_xor(z, 32);
        rzl[jm] = 1.0f / z;
    }

    // ---- y_norm -> LDS: y_lds[m][c] bf16, rows 512B, XOR-swizzled 16B granule ----
#pragma unroll
    for (int jc = 0; jc < 8; ++jc) {
#pragma unroll
        for (int jm = 0; jm < 4; ++jm) {
            int mloc = wm * 64 + jm * 16 + cr;
            int cb = (wc * 256 + jc * 32 + q * 8) ^ ((mloc & 7) << 4);
            s16x4 v;
#pragma unroll
            for (int r = 0; r < 4; ++r) v[r] = f2bf(acc[jc][jm][r] * rzl[jm]);
            *(s16x4*)(smem + mloc * 512 + cb) = v;
        }
    }
    __syncthreads();

    // ---- GEMM2: o[c_out][m] = wv[c_out][:] . y_norm[:][m], K=256 ----
    int co0 = w * 64;
    f32x4 acc2[4][8];
#pragma unroll
    for (int j2 = 0; j2 < 4; ++j2)
#pragma unroll
        for (int jm2 = 0; jm2 < 8; ++jm2) acc2[j2][jm2] = (f32x4){0.f, 0.f, 0.f, 0.f};

#pragma unroll 2
    for (int ks = 0; ks < 8; ++ks) {
        s16x8 a2[4];
#pragma unroll
        for (int j2 = 0; j2 < 4; ++j2) {
            const float* wr = wv + (size_t)(co0 + j2 * 16 + cr) * CQ + ks * 32 + q * 8;
            float4 wa = ld4(wr);
            float4 wb = ld4(wr + 4);
            a2[j2][0] = f2bf(wa.x); a2[j2][1] = f2bf(wa.y);
            a2[j2][2] = f2bf(wa.z); a2[j2][3] = f2bf(wa.w);
            a2[j2][4] = f2bf(wb.x); a2[j2][5] = f2bf(wb.y);
            a2[j2][6] = f2bf(wb.z); a2[j2][7] = f2bf(wb.w);
        }
#pragma unroll
        for (int jm2 = 0; jm2 < 8; ++jm2) {
            int mloc = jm2 * 16 + cr;
            s16x8 b2 = *(const s16x8*)(smem + mloc * 512 + ((ks * 64 + q * 16) ^ ((mloc & 7) << 4)));
#pragma unroll
            for (int j2 = 0; j2 < 4; ++j2)
                acc2[j2][jm2] = __builtin_amdgcn_mfma_f32_16x16x32_bf16(a2[j2], b2, acc2[j2][jm2], 0, 0, 0);
        }
    }

    // ---- epilogue: out = (1-gam)*acc2 (+ gam*x), nontemporal stores ----
    float gam = gamma[0];
    float omg = 1.f - gam;
    if (gam != 0.f) {
#pragma unroll
        for (int j2 = 0; j2 < 4; ++j2)
#pragma unroll
            for (int jm2 = 0; jm2 < 8; ++jm2)
#pragma unroll
                for (int r = 0; r < 4; ++r) {
                    int c_out = co0 + j2 * 16 + q * 4 + r;
                    size_t idx = ((size_t)b * CQ + c_out) * NQ + m0 + jm2 * 16 + cr;
                    __builtin_nontemporal_store(
                        fmaf(gam, x[idx], acc2[j2][jm2][r] * omg), out + idx);
                }
    } else {
#pragma unroll
        for (int j2 = 0; j2 < 4; ++j2)
#pragma unroll
            for (int jm2 = 0; jm2 < 8; ++jm2)
#pragma unroll
                for (int r = 0; r < 4; ++r) {
                    int c_out = co0 + j2 * 16 + q * 4 + r;
                    size_t idx = ((size_t)b * CQ + c_out) * NQ + m0 + jm2 * 16 + cr;
                    __builtin_nontemporal_store(acc2[j2][jm2][r] * omg, out + idx);
                }
    }
}

extern "C" void kernel_launch(void* const* d_in, const int* in_sizes, int n_in,
                              void* d_out, int out_size, void* d_ws, size_t ws_size,
                              hipStream_t stream) {
    const float* x     = (const float*)d_in[0];
    const float* wq    = (const float*)d_in[1];
    const float* wk    = (const float*)d_in[2];
    const float* wv    = (const float*)d_in[3];
    const float* gamma = (const float*)d_in[4];
    float* out = (float*)d_out;

    // ws (floats): fs[B*N] | g[B*N] | fmx[B] | fmn[B] | pad -> xbf (bf16) [B*C*N]  (~17.1MB)
    float* ws  = (float*)d_ws;
    float* fs  = ws;
    float* g   = ws + BQ * NQ;
    float* fmx = ws + 2 * BQ * NQ;
    float* fmn = fmx + BQ;
    short* xbf = (short*)(ws + 2 * BQ * NQ + 64);

    hipLaunchKernelGGL(k_fg, dim3(NQ / 64, BQ), dim3(256), 0, stream, x, wq, wk, fs, g, xbf);
    hipLaunchKernelGGL(k_minmax, dim3(BQ), dim3(256), 0, stream, fs, fmx, fmn);
    hipLaunchKernelGGL(k_attn, dim3(BQ * (NQ / MT)), dim3(256), 0, stream,
                       xbf, fs, g, fmx, fmn, wv, x, gamma, out);
}